// Round 7
// baseline (278.408 us; speedup 1.0000x reference)
//
#include <hip/hip_runtime.h>
#include <stdint.h>

// SimpleMarkovModel: 2-state Markov chain, 200000 emitters x 500 frames.
// Bit-exact JAX partitionable Threefry-2x32 (verified rounds 1-6, absmax 0).
//
// R7: maximize TLP. One emitter per THREAD (3125 waves, ~3 waves/SIMD, 2x
// round 6) so the ~220-cycle per-frame dependency critical path and the
// SMEM/store waits are hidden by wave interleaving instead of being exposed
// at 1.5 waves/SIMD. Keeps: nt stores, 4-frame unroll with independent
// store-value regs, group-of-4 double-buffered s_load_dwordx4 subkeys,
// SALU key schedule.

#define ROTL32(x, d) __builtin_amdgcn_alignbit((x), (x), 32 - (d))

__device__ __forceinline__ void tf2x32(uint32_t k0, uint32_t k1,
                                       uint32_t x0, uint32_t x1,
                                       uint32_t& o0, uint32_t& o1) {
  const uint32_t k2 = k0 ^ k1 ^ 0x1BD11BDAu;
  x0 += k0; x1 += k1;
#define TF_R(d) { x0 += x1; x1 = ROTL32(x1, d) ^ x0; }
  TF_R(13) TF_R(15) TF_R(26) TF_R(6)
  x0 += k1; x1 += k2 + 1u;
  TF_R(17) TF_R(29) TF_R(16) TF_R(24)
  x0 += k2; x1 += k0 + 2u;
  TF_R(13) TF_R(15) TF_R(26) TF_R(6)
  x0 += k0; x1 += k1 + 3u;
  TF_R(17) TF_R(29) TF_R(16) TF_R(24)
  x0 += k1; x1 += k2 + 4u;
  TF_R(13) TF_R(15) TF_R(26) TF_R(6)
  x0 += k2; x1 += k0 + 5u;
#undef TF_R
  o0 = x0; o1 = x1;
}

// Subkey table, zero-padded to cap so the group prefetch never branches.
__global__ void subkeys_kernel(uint2* __restrict__ ks, int nf, int cap) {
  const int f = blockIdx.x * blockDim.x + threadIdx.x;
  if (f < nf) {
    uint32_t a, b;
    tf2x32(0u, 42u, 0u, (uint32_t)f, a, b);
    ks[f] = make_uint2(a, b);
  } else if (f < cap) {
    ks[f] = make_uint2(0u, 0u);
  }
}

// One frame, ONE chain. Returns the output word for this frame.
__device__ __forceinline__ uint32_t do_frame1(
    uint32_t k0, uint32_t k1, uint32_t& s, uint32_t& thr, uint32_t base,
    uint32_t tsh0, uint32_t tsh1, uint32_t sw0, uint32_t sw1) {
  const uint32_t k2 = k0 ^ k1 ^ 0x1BD11BDAu;   // SALU
  const uint32_t c1 = k2 + 1u, c2 = k0 + 2u, c3 = k1 + 3u,
                 c4 = k2 + 4u, c5 = k0 + 5u;   // SALU

  uint32_t x0 = k0, x1 = base + s + k1;        // v_add3
#define RND(d) { x0 += x1; x1 = ROTL32(x1, (d)) ^ x0; }
  RND(13) RND(15) RND(26) RND(6)
  x0 += k1; x1 += c1;
  RND(17) RND(29) RND(16) RND(24)
  x0 += k2; x1 += c2;
  RND(13) RND(15) RND(26) RND(6)
  x0 += k0; x1 += c3;
  RND(17) RND(29) RND(16) RND(24)
  x0 += k1; x1 += c4;
  RND(13) RND(15) RND(26) RND(6)
  x0 += k2; x1 += c5;
#undef RND

  s ^= ((x0 ^ x1) < thr) ? sw1 : sw0;
  thr = s ? tsh1 : tsh0;
  return s ? 0u : 0x3f800000u;
}

__device__ __forceinline__ void markov_body(
    const float* __restrict__ initial, const float* __restrict__ transition,
    const float* __restrict__ tmat, const uint2* __restrict__ ks,
    float* __restrict__ out, int N, int nf) {
  const int n = blockIdx.x * blockDim.x + threadIdx.x;
  if (n >= N) return;

  // u < p  <=>  bits < (ceil(p*2^23) << 9); clamp guards p ~ 1.0.
  const uint64_t t0w = ((uint64_t)(uint32_t)ceilf(transition[1] * 8388608.0f)) << 9;
  const uint64_t t1w = ((uint64_t)(uint32_t)ceilf(transition[3] * 8388608.0f)) << 9;
  const uint32_t tsh0 = (t0w > 0xFFFFFFFFull) ? 0xFFFFFFFFu : (uint32_t)t0w;
  const uint32_t tsh1 = (t1w > 0xFFFFFFFFull) ? 0xFFFFFFFFu : (uint32_t)t1w;
  const uint32_t sw0 = (tmat[1] != 0.0f) ? 1u : 0u;  // matrix 0 swaps?
  const uint32_t sw1 = (tmat[5] != 0.0f) ? 1u : 0u;  // matrix 1 swaps?

  uint32_t s = (initial[2 * n] != 0.0f) ? 0u : 1u;
  uint32_t thr = s ? tsh1 : tsh0;
  const uint32_t base = 2u * (uint32_t)n;      // threefry counter = 2n + s

  uint32_t* op = (uint32_t*)(out + n);         // advances by N per frame
  const uint4* kq = (const uint4*)ks;          // 2 subkeys per uint4

  const int ng = nf / 4;
  uint4 a0 = kq[0], a1 = kq[1];
  for (int g = 0; g < ng; ++g) {
    const uint4 b0 = kq[2 * g + 2];            // next group (padded)
    const uint4 b1 = kq[2 * g + 3];
    // 4 frames, 4 independent value regs -> 4 outstanding nt stores.
    const uint32_t v0 = do_frame1(a0.x, a0.y, s, thr, base, tsh0, tsh1, sw0, sw1);
    __builtin_nontemporal_store(v0, op); op += N;
    const uint32_t v1 = do_frame1(a0.z, a0.w, s, thr, base, tsh0, tsh1, sw0, sw1);
    __builtin_nontemporal_store(v1, op); op += N;
    const uint32_t v2 = do_frame1(a1.x, a1.y, s, thr, base, tsh0, tsh1, sw0, sw1);
    __builtin_nontemporal_store(v2, op); op += N;
    const uint32_t v3 = do_frame1(a1.z, a1.w, s, thr, base, tsh0, tsh1, sw0, sw1);
    __builtin_nontemporal_store(v3, op); op += N;
    a0 = b0; a1 = b1;
  }
  for (int f = ng * 4; f < nf; ++f) {          // tail (empty for nf%4==0)
    const uint2 k = ks[f];
    const uint32_t v = do_frame1(k.x, k.y, s, thr, base, tsh0, tsh1, sw0, sw1);
    __builtin_nontemporal_store(v, op); op += N;
  }
}

__global__ __launch_bounds__(256) void markov_kernel(
    const float* __restrict__ initial, const float* __restrict__ transition,
    const float* __restrict__ tmat, const uint2* __restrict__ ks,
    float* __restrict__ out, int N, int nf) {
  markov_body(initial, transition, tmat, ks, out, N, nf);
}

// Fallback if d_ws too small: subkeys in LDS (same padded layout).
__global__ __launch_bounds__(256) void markov_kernel_lds(
    const float* __restrict__ initial, const float* __restrict__ transition,
    const float* __restrict__ tmat, float* __restrict__ out,
    int N, int nf, int cap) {
  extern __shared__ uint2 kf[];
  for (int f = threadIdx.x; f < cap; f += blockDim.x) {
    uint2 k = make_uint2(0u, 0u);
    if (f < nf) {
      uint32_t a, b;
      tf2x32(0u, 42u, 0u, (uint32_t)f, a, b);
      k = make_uint2(a, b);
    }
    kf[f] = k;
  }
  __syncthreads();
  markov_body(initial, transition, tmat, kf, out, N, nf);
}

extern "C" void kernel_launch(void* const* d_in, const int* in_sizes, int n_in,
                              void* d_out, int out_size, void* d_ws, size_t ws_size,
                              hipStream_t stream) {
  const float* initial    = (const float*)d_in[0];
  const float* transition = (const float*)d_in[1];
  const float* tmat       = (const float*)d_in[2];
  float* out = (float*)d_out;

  const int N  = in_sizes[0] / 2;               // 200000 emitters
  const int nf = (N > 0) ? (out_size / N) : 0;  // 500 frames
  if (N <= 0 || nf <= 0) return;

  const int block = 256;
  const int grid = (N + block - 1) / block;     // 782 blocks = 3128 waves

  const int cap = (nf / 4 + 2) * 4;             // padded subkey count
  const size_t need = (size_t)cap * sizeof(uint2);
  if (ws_size >= need) {
    uint2* ks = (uint2*)d_ws;
    subkeys_kernel<<<(cap + 255) / 256, 256, 0, stream>>>(ks, nf, cap);
    markov_kernel<<<grid, block, 0, stream>>>(initial, transition, tmat, ks,
                                              out, N, nf);
  } else {
    markov_kernel_lds<<<grid, block, need, stream>>>(initial, transition,
                                                     tmat, out, N, nf, cap);
  }
}

// Round 8
// 270.319 us; speedup vs baseline: 1.0299x; 1.0299x over previous
//
#include <hip/hip_runtime.h>
#include <stdint.h>

// SimpleMarkovModel: 2-state Markov chain, 200000 emitters x 500 frames.
// Bit-exact JAX partitionable Threefry-2x32 (verified rounds 1-7, absmax 0).
//
// R8: break the per-frame store->register-reuse vmcnt coupling.
// Evidence: per-eval wall cost ~440 SIMD-cyc invariant to wave count and ALU
// diet; VGPR_Count=12 shows all "independent" store values were coalesced
// into 1-2 registers -> s_waitcnt vmcnt every frame on store-ack (~1000 cyc).
// Fix: batches of 16 frames; 16 values computed into 16 registers whose
// liveness (store deferred to batch end) FORCES distinct allocation; one
// vmcnt recycle point per 16 frames instead of per frame.

#define ROTL32(x, d) __builtin_amdgcn_alignbit((x), (x), 32 - (d))

#define BATCH 16

__device__ __forceinline__ void tf2x32(uint32_t k0, uint32_t k1,
                                       uint32_t x0, uint32_t x1,
                                       uint32_t& o0, uint32_t& o1) {
  const uint32_t k2 = k0 ^ k1 ^ 0x1BD11BDAu;
  x0 += k0; x1 += k1;
#define TF_R(d) { x0 += x1; x1 = ROTL32(x1, d) ^ x0; }
  TF_R(13) TF_R(15) TF_R(26) TF_R(6)
  x0 += k1; x1 += k2 + 1u;
  TF_R(17) TF_R(29) TF_R(16) TF_R(24)
  x0 += k2; x1 += k0 + 2u;
  TF_R(13) TF_R(15) TF_R(26) TF_R(6)
  x0 += k0; x1 += k1 + 3u;
  TF_R(17) TF_R(29) TF_R(16) TF_R(24)
  x0 += k1; x1 += k2 + 4u;
  TF_R(13) TF_R(15) TF_R(26) TF_R(6)
  x0 += k2; x1 += k0 + 5u;
#undef TF_R
  o0 = x0; o1 = x1;
}

// Subkey table, zero-padded to cap.
__global__ void subkeys_kernel(uint2* __restrict__ ks, int nf, int cap) {
  const int f = blockIdx.x * blockDim.x + threadIdx.x;
  if (f < nf) {
    uint32_t a, b;
    tf2x32(0u, 42u, 0u, (uint32_t)f, a, b);
    ks[f] = make_uint2(a, b);
  } else if (f < cap) {
    ks[f] = make_uint2(0u, 0u);
  }
}

// One frame, one chain; returns the output word.
__device__ __forceinline__ uint32_t do_frame1(
    uint32_t k0, uint32_t k1, uint32_t& s, uint32_t& thr, uint32_t base,
    uint32_t tsh0, uint32_t tsh1, uint32_t sw0, uint32_t sw1) {
  const uint32_t k2 = k0 ^ k1 ^ 0x1BD11BDAu;   // SALU
  const uint32_t c1 = k2 + 1u, c2 = k0 + 2u, c3 = k1 + 3u,
                 c4 = k2 + 4u, c5 = k0 + 5u;   // SALU

  uint32_t x0 = k0, x1 = base + s + k1;        // v_add3
#define RND(d) { x0 += x1; x1 = ROTL32(x1, (d)) ^ x0; }
  RND(13) RND(15) RND(26) RND(6)
  x0 += k1; x1 += c1;
  RND(17) RND(29) RND(16) RND(24)
  x0 += k2; x1 += c2;
  RND(13) RND(15) RND(26) RND(6)
  x0 += k0; x1 += c3;
  RND(17) RND(29) RND(16) RND(24)
  x0 += k1; x1 += c4;
  RND(13) RND(15) RND(26) RND(6)
  x0 += k2; x1 += c5;
#undef RND

  s ^= ((x0 ^ x1) < thr) ? sw1 : sw0;
  thr = s ? tsh1 : tsh0;
  return s ? 0u : 0x3f800000u;
}

__device__ __forceinline__ void markov_body(
    const float* __restrict__ initial, const float* __restrict__ transition,
    const float* __restrict__ tmat, const uint2* __restrict__ ks,
    float* __restrict__ out, int N, int nf) {
  const int n = blockIdx.x * blockDim.x + threadIdx.x;
  if (n >= N) return;

  // u < p  <=>  bits < (ceil(p*2^23) << 9); clamp guards p ~ 1.0.
  const uint64_t t0w = ((uint64_t)(uint32_t)ceilf(transition[1] * 8388608.0f)) << 9;
  const uint64_t t1w = ((uint64_t)(uint32_t)ceilf(transition[3] * 8388608.0f)) << 9;
  const uint32_t tsh0 = (t0w > 0xFFFFFFFFull) ? 0xFFFFFFFFu : (uint32_t)t0w;
  const uint32_t tsh1 = (t1w > 0xFFFFFFFFull) ? 0xFFFFFFFFu : (uint32_t)t1w;
  const uint32_t sw0 = (tmat[1] != 0.0f) ? 1u : 0u;  // matrix 0 swaps?
  const uint32_t sw1 = (tmat[5] != 0.0f) ? 1u : 0u;  // matrix 1 swaps?

  uint32_t s = (initial[2 * n] != 0.0f) ? 0u : 1u;
  uint32_t thr = s ? tsh1 : tsh0;
  const uint32_t base = 2u * (uint32_t)n;      // threefry counter = 2n + s

  uint32_t* op = (uint32_t*)(out + n);         // wave-coalesced column

  const int nb = nf / BATCH;                   // full batches (31 for nf=500)
  for (int b = 0; b < nb; ++b) {
    const int f0 = b * BATCH;
    uint32_t vals[BATCH];                      // 16 distinct live registers
#pragma unroll
    for (int i = 0; i < BATCH; ++i) {          // compile-time indices only
      const uint2 k = ks[f0 + i];              // uniform -> s_load, pipelined
      vals[i] = do_frame1(k.x, k.y, s, thr, base, tsh0, tsh1, sw0, sw1);
    }
#pragma unroll
    for (int i = 0; i < BATCH; ++i) {
      __builtin_nontemporal_store(vals[i], op + (size_t)(f0 + i) * N);
    }
  }
  for (int f = nb * BATCH; f < nf; ++f) {      // tail (4 frames for nf=500)
    const uint2 k = ks[f];
    const uint32_t v = do_frame1(k.x, k.y, s, thr, base, tsh0, tsh1, sw0, sw1);
    __builtin_nontemporal_store(v, op + (size_t)f * N);
  }
}

__global__ __launch_bounds__(256) void markov_kernel(
    const float* __restrict__ initial, const float* __restrict__ transition,
    const float* __restrict__ tmat, const uint2* __restrict__ ks,
    float* __restrict__ out, int N, int nf) {
  markov_body(initial, transition, tmat, ks, out, N, nf);
}

// Fallback if d_ws too small: subkeys in LDS (same layout).
__global__ __launch_bounds__(256) void markov_kernel_lds(
    const float* __restrict__ initial, const float* __restrict__ transition,
    const float* __restrict__ tmat, float* __restrict__ out,
    int N, int nf, int cap) {
  extern __shared__ uint2 kf[];
  for (int f = threadIdx.x; f < cap; f += blockDim.x) {
    uint2 k = make_uint2(0u, 0u);
    if (f < nf) {
      uint32_t a, b;
      tf2x32(0u, 42u, 0u, (uint32_t)f, a, b);
      k = make_uint2(a, b);
    }
    kf[f] = k;
  }
  __syncthreads();
  markov_body(initial, transition, tmat, kf, out, N, nf);
}

extern "C" void kernel_launch(void* const* d_in, const int* in_sizes, int n_in,
                              void* d_out, int out_size, void* d_ws, size_t ws_size,
                              hipStream_t stream) {
  const float* initial    = (const float*)d_in[0];
  const float* transition = (const float*)d_in[1];
  const float* tmat       = (const float*)d_in[2];
  float* out = (float*)d_out;

  const int N  = in_sizes[0] / 2;               // 200000 emitters
  const int nf = (N > 0) ? (out_size / N) : 0;  // 500 frames
  if (N <= 0 || nf <= 0) return;

  const int block = 256;
  const int grid = (N + block - 1) / block;     // 782 blocks = 3128 waves

  const int cap = ((nf + BATCH - 1) / BATCH + 1) * BATCH;  // padded count
  const size_t need = (size_t)cap * sizeof(uint2);
  if (ws_size >= need) {
    uint2* ks = (uint2*)d_ws;
    subkeys_kernel<<<(cap + 255) / 256, 256, 0, stream>>>(ks, nf, cap);
    markov_kernel<<<grid, block, 0, stream>>>(initial, transition, tmat, ks,
                                              out, N, nf);
  } else {
    markov_kernel_lds<<<grid, block, need, stream>>>(initial, transition,
                                                     tmat, out, N, nf, cap);
  }
}

// Round 9
// 265.572 us; speedup vs baseline: 1.0483x; 1.0179x over previous
//
#include <hip/hip_runtime.h>
#include <stdint.h>

// SimpleMarkovModel: 2-state Markov chain, 200000 emitters x 500 frames.
// Bit-exact JAX partitionable Threefry-2x32 (verified rounds 1-8, absmax 0).
//
// R9: VALU instruction diet. Evidence says we sit at the chip's practical
// VALU-issue ceiling (~66%, = m07's measured scalar-ALU ceiling; effective
// clock ~1.25 GHz under sustained dense VALU load), so wall time tracks
// VALU op count. Cuts:
//  - key injections folded into the next round's add via v_add3 (-4/frame)
//  - x0 init folded into round 1: x0 = k0 + x1in (-1)
//  - state kept as bool -> SGPR lane-mask (s_xor_b64 free) feeding cndmask
//  - uniform column pointer -> saddr stores (0 VALU addressing)
//  - 8-frame groups: keys hoisted, 8 nt stores batched
//  - wave-uniform specialization for the actual (sw0=0, sw1=1) structure

#define ROTL32(x, d) __builtin_amdgcn_alignbit((x), (x), 32 - (d))

__device__ __forceinline__ void tf2x32(uint32_t k0, uint32_t k1,
                                       uint32_t x0, uint32_t x1,
                                       uint32_t& o0, uint32_t& o1) {
  const uint32_t k2 = k0 ^ k1 ^ 0x1BD11BDAu;
  x0 += k0; x1 += k1;
#define TF_R(d) { x0 += x1; x1 = ROTL32(x1, d) ^ x0; }
  TF_R(13) TF_R(15) TF_R(26) TF_R(6)
  x0 += k1; x1 += k2 + 1u;
  TF_R(17) TF_R(29) TF_R(16) TF_R(24)
  x0 += k2; x1 += k0 + 2u;
  TF_R(13) TF_R(15) TF_R(26) TF_R(6)
  x0 += k0; x1 += k1 + 3u;
  TF_R(17) TF_R(29) TF_R(16) TF_R(24)
  x0 += k1; x1 += k2 + 4u;
  TF_R(13) TF_R(15) TF_R(26) TF_R(6)
  x0 += k2; x1 += k0 + 5u;
#undef TF_R
  o0 = x0; o1 = x1;
}

// Subkey table, zero-padded to cap.
__global__ void subkeys_kernel(uint2* __restrict__ ks, int nf, int cap) {
  const int f = blockIdx.x * blockDim.x + threadIdx.x;
  if (f < nf) {
    uint32_t a, b;
    tf2x32(0u, 42u, 0u, (uint32_t)f, a, b);
    ks[f] = make_uint2(a, b);
  } else if (f < cap) {
    ks[f] = make_uint2(0u, 0u);
  }
}

// Lean cipher: x1in = counter + k1 precomputed; injections folded via add3.
// Returns hi^lo of threefry2x32((k0,k1),(0,counter)).
__device__ __forceinline__ uint32_t cipher(uint32_t k0, uint32_t k1,
                                           uint32_t x1in) {
  const uint32_t k2 = k0 ^ k1 ^ 0x1BD11BDAu;  // SALU when keys uniform
  const uint32_t c1 = k2 + 1u, c2 = k0 + 2u, c3 = k1 + 3u,
                 c4 = k2 + 4u, c5 = k0 + 5u;  // SALU

  uint32_t x0 = k0 + x1in;                    // round 1 add folded with init
  uint32_t x1 = ROTL32(x1in, 13) ^ x0;
  x0 += x1; x1 = ROTL32(x1, 15) ^ x0;
  x0 += x1; x1 = ROTL32(x1, 26) ^ x0;
  x0 += x1; x1 = ROTL32(x1,  6) ^ x0;
  x1 += c1; x0 = x0 + k1 + x1;                // inj1 folded (add3)
  x1 = ROTL32(x1, 17) ^ x0;
  x0 += x1; x1 = ROTL32(x1, 29) ^ x0;
  x0 += x1; x1 = ROTL32(x1, 16) ^ x0;
  x0 += x1; x1 = ROTL32(x1, 24) ^ x0;
  x1 += c2; x0 = x0 + k2 + x1;                // inj2 folded
  x1 = ROTL32(x1, 13) ^ x0;
  x0 += x1; x1 = ROTL32(x1, 15) ^ x0;
  x0 += x1; x1 = ROTL32(x1, 26) ^ x0;
  x0 += x1; x1 = ROTL32(x1,  6) ^ x0;
  x1 += c3; x0 = x0 + k0 + x1;                // inj3 folded
  x1 = ROTL32(x1, 17) ^ x0;
  x0 += x1; x1 = ROTL32(x1, 29) ^ x0;
  x0 += x1; x1 = ROTL32(x1, 16) ^ x0;
  x0 += x1; x1 = ROTL32(x1, 24) ^ x0;
  x1 += c4; x0 = x0 + k1 + x1;                // inj4 folded
  x1 = ROTL32(x1, 13) ^ x0;
  x0 += x1; x1 = ROTL32(x1, 15) ^ x0;
  x0 += x1; x1 = ROTL32(x1, 26) ^ x0;
  x0 += x1; x1 = ROTL32(x1,  6) ^ x0;
  return (x0 + k2) ^ (x1 + c5);               // final inj + output xor
}

// Fast path: sw0 == 0 && sw1 == 1 (identity / swap transition matrices,
// the actual problem instance). State as bool -> SGPR lane-mask.
__device__ __forceinline__ void run_fast(
    const uint2* __restrict__ ks, float* __restrict__ out, int n, int N,
    int nf, bool s, uint32_t tsh0, uint32_t tsh1) {
  const uint32_t base = 2u * (uint32_t)n;
  uint32_t thr = s ? tsh1 : tsh0;
  float* col = out;                       // wave-uniform; advances by N

  const int ng = nf / 8;
  for (int g = 0; g < ng; ++g) {
    const int f0 = g * 8;
    // hoisted uniform key loads for the group (s_load_dwordx*)
    uint2 k[8];
#pragma unroll
    for (int i = 0; i < 8; ++i) k[i] = ks[f0 + i];

    uint32_t vals[8];
#pragma unroll
    for (int i = 0; i < 8; ++i) {
      const uint32_t x1in = base + (s ? 1u : 0u) + k[i].y;   // add3
      const uint32_t r = cipher(k[i].x, k[i].y, x1in);
      s = s != (r < thr);                 // s_xor_b64 on lane-mask
      thr = s ? tsh1 : tsh0;              // cndmask from mask
      vals[i] = s ? 0u : 0x3f800000u;     // cndmask from mask
    }
#pragma unroll
    for (int i = 0; i < 8; ++i) {
      __builtin_nontemporal_store(vals[i], (uint32_t*)(col + (size_t)i * N) + n);
    }
    col += (size_t)8 * N;
  }
  for (int f = ng * 8; f < nf; ++f) {     // tail (4 frames for nf=500)
    const uint2 kk = ks[f];
    const uint32_t x1in = base + (s ? 1u : 0u) + kk.y;
    const uint32_t r = cipher(kk.x, kk.y, x1in);
    s = s != (r < thr);
    thr = s ? tsh1 : tsh0;
    __builtin_nontemporal_store(s ? 0u : 0x3f800000u, (uint32_t*)col + n);
    col += N;
  }
}

// General path: arbitrary swap flags (correctness fallback).
__device__ __forceinline__ void run_general(
    const uint2* __restrict__ ks, float* __restrict__ out, int n, int N,
    int nf, uint32_t s, uint32_t tsh0, uint32_t tsh1,
    uint32_t sw0, uint32_t sw1) {
  const uint32_t base = 2u * (uint32_t)n;
  uint32_t thr = s ? tsh1 : tsh0;
  float* col = out;
  for (int f = 0; f < nf; ++f) {
    const uint2 kk = ks[f];
    const uint32_t r = cipher(kk.x, kk.y, base + s + kk.y);
    s ^= (r < thr) ? sw1 : sw0;
    thr = s ? tsh1 : tsh0;
    __builtin_nontemporal_store(s ? 0u : 0x3f800000u, (uint32_t*)col + n);
    col += N;
  }
}

__device__ __forceinline__ void markov_body(
    const float* __restrict__ initial, const float* __restrict__ transition,
    const float* __restrict__ tmat, const uint2* __restrict__ ks,
    float* __restrict__ out, int N, int nf) {
  const int n = blockIdx.x * blockDim.x + threadIdx.x;
  if (n >= N) return;

  // u < p  <=>  bits < (ceil(p*2^23) << 9); clamp guards p ~ 1.0.
  const uint64_t t0w = ((uint64_t)(uint32_t)ceilf(transition[1] * 8388608.0f)) << 9;
  const uint64_t t1w = ((uint64_t)(uint32_t)ceilf(transition[3] * 8388608.0f)) << 9;
  const uint32_t tsh0 = (t0w > 0xFFFFFFFFull) ? 0xFFFFFFFFu : (uint32_t)t0w;
  const uint32_t tsh1 = (t1w > 0xFFFFFFFFull) ? 0xFFFFFFFFu : (uint32_t)t1w;
  const uint32_t sw0 = (tmat[1] != 0.0f) ? 1u : 0u;  // matrix 0 swaps?
  const uint32_t sw1 = (tmat[5] != 0.0f) ? 1u : 0u;  // matrix 1 swaps?

  const bool s0 = (initial[2 * n] == 0.0f);  // true -> state 1 ("off")

  if (sw0 == 0u && sw1 == 1u) {              // wave-uniform branch
    run_fast(ks, out, n, N, nf, s0, tsh0, tsh1);
  } else {
    run_general(ks, out, n, N, nf, s0 ? 1u : 0u, tsh0, tsh1, sw0, sw1);
  }
}

__global__ __launch_bounds__(256) void markov_kernel(
    const float* __restrict__ initial, const float* __restrict__ transition,
    const float* __restrict__ tmat, const uint2* __restrict__ ks,
    float* __restrict__ out, int N, int nf) {
  markov_body(initial, transition, tmat, ks, out, N, nf);
}

// Fallback if d_ws too small: subkeys in LDS (same layout).
__global__ __launch_bounds__(256) void markov_kernel_lds(
    const float* __restrict__ initial, const float* __restrict__ transition,
    const float* __restrict__ tmat, float* __restrict__ out,
    int N, int nf, int cap) {
  extern __shared__ uint2 kf[];
  for (int f = threadIdx.x; f < cap; f += blockDim.x) {
    uint2 k = make_uint2(0u, 0u);
    if (f < nf) {
      uint32_t a, b;
      tf2x32(0u, 42u, 0u, (uint32_t)f, a, b);
      k = make_uint2(a, b);
    }
    kf[f] = k;
  }
  __syncthreads();
  markov_body(initial, transition, tmat, kf, out, N, nf);
}

extern "C" void kernel_launch(void* const* d_in, const int* in_sizes, int n_in,
                              void* d_out, int out_size, void* d_ws, size_t ws_size,
                              hipStream_t stream) {
  const float* initial    = (const float*)d_in[0];
  const float* transition = (const float*)d_in[1];
  const float* tmat       = (const float*)d_in[2];
  float* out = (float*)d_out;

  const int N  = in_sizes[0] / 2;               // 200000 emitters
  const int nf = (N > 0) ? (out_size / N) : 0;  // 500 frames
  if (N <= 0 || nf <= 0) return;

  const int block = 256;
  const int grid = (N + block - 1) / block;     // 782 blocks = 3128 waves

  const int cap = ((nf + 7) / 8 + 1) * 8;       // padded subkey count
  const size_t need = (size_t)cap * sizeof(uint2);
  if (ws_size >= need) {
    uint2* ks = (uint2*)d_ws;
    subkeys_kernel<<<(cap + 255) / 256, 256, 0, stream>>>(ks, nf, cap);
    markov_kernel<<<grid, block, 0, stream>>>(initial, transition, tmat, ks,
                                              out, N, nf);
  } else {
    markov_kernel_lds<<<grid, block, need, stream>>>(initial, transition,
                                                     tmat, out, N, nf, cap);
  }
}